// Round 4
// baseline (1298.508 us; speedup 1.0000x reference)
//
#include <hip/hip_runtime.h>

// LSTMPredictor: 2-layer LSTMCell (H=51), L=1000 steps + 100 autoregressive,
// B=256 chains. One block/batch element, 768 threads in 3 groups of 204:
//   G0 (tid   0..203): row j of W_hh1 -> gates1 partial (for h1(t+1))
//   G1 (tid 256..459): row j of W_ih2 -> gatesA(t)
//   G2 (tid 512..715): row j of W_hh2 -> gatesB(t)
// KEY FIX vs R3: weight row held in 13 *named* float4 SSA variables (w0..w12)
// — the array form was never SROA'd and lived in scratch (VGPR_Count=52 tell).
// Output projection moved OFF the hot-loop critical path: tid 204..207 compute
// out(t-1) from stable h2s concurrently with phase-A matvecs.
// Hot loop (t=0..998): 2 barriers/step. Future loop (x<-out_s): 3 barriers.

#define B_   256
#define L_   1000
#define H_   51
#define HP   52
#define G4   204
#define GP   208
#define T_   1100

__device__ __forceinline__ float frcp(float v) { return __builtin_amdgcn_rcpf(v); }
__device__ __forceinline__ float sigf(float v) {
    return frcp(1.0f + __expf(-v));
}
__device__ __forceinline__ float tanh_fast(float v) {
    float a = fminf(fmaxf(v, -9.0f), 9.0f);
    float e = __expf(2.0f * a);
    return (e - 1.0f) * frcp(e + 1.0f);
}

#define LDW(i) do { w##i.x = wrow[4*(i)+0]; w##i.y = wrow[4*(i)+1]; \
                    w##i.z = wrow[4*(i)+2]; w##i.w = wrow[4*(i)+3]; } while(0)

#define DOT(i) do { float4 hv = h4[(i)]; \
                    a0 = fmaf(w##i.x, hv.x, a0); a1 = fmaf(w##i.y, hv.y, a1); \
                    a2 = fmaf(w##i.z, hv.z, a2); a3 = fmaf(w##i.w, hv.w, a3); } while(0)

#define MATVEC() do { const float4* h4 = (const float4*)hs[s]; \
        float a0 = bias, a1 = 0.f, a2 = 0.f, a3 = 0.f; \
        DOT(0); DOT(1); DOT(2); DOT(3); DOT(4); DOT(5); DOT(6); \
        DOT(7); DOT(8); DOT(9); DOT(10); DOT(11); DOT(12); \
        gdst[0] = (a0 + a1) + (a2 + a3); } while(0)

__global__ __launch_bounds__(768, 3)
void lstm_pred_kernel(const float* __restrict__ x,
                      const float* __restrict__ W_ih1, const float* __restrict__ W_hh1,
                      const float* __restrict__ b_ih1, const float* __restrict__ b_hh1,
                      const float* __restrict__ W_ih2, const float* __restrict__ W_hh2,
                      const float* __restrict__ b_ih2, const float* __restrict__ b_hh2,
                      const float* __restrict__ W_lin, const float* __restrict__ b_lin,
                      float* __restrict__ out)
{
    __shared__ float xrow[L_];
    __shared__ alignas(16) float gall[3 * GP];  // [0..)=g1partial, [GP..)=gA, [2GP..)=gB
    __shared__ alignas(16) float hs[2][HP];     // hs[0]=h1, hs[1]=h2
    __shared__ float wlin_s[HP];
    __shared__ float out_s;

    const int tid = threadIdx.x;
    const int b   = blockIdx.x;
    const int g   = tid >> 8;
    const int j   = tid & 255;
    const bool act = (j < G4);
    const int  s   = (g == 2) ? 1 : 0;

    for (int i = tid; i < L_; i += 768) xrow[i] = x[(size_t)b * L_ + i];
    if (tid < HP) {
        hs[0][tid] = 0.0f; hs[1][tid] = 0.0f;
        wlin_s[tid] = (tid < H_) ? W_lin[tid] : 0.0f;
    }

    // ---- one weight row per thread, in NAMED registers ----
    const float* wrow = (g == 0) ? (W_hh1 + j * H_)
                      : (g == 1) ? (W_ih2 + j * H_)
                                 : (W_hh2 + j * H_);
    float bias = 0.0f;
    float4 z4 = make_float4(0.f, 0.f, 0.f, 0.f);
    float4 w0=z4, w1=z4, w2=z4, w3=z4, w4=z4, w5=z4, w6=z4,
           w7=z4, w8=z4, w9=z4, w10=z4, w11=z4, w12=z4;
    if (act) {
        if (g == 0)      bias = b_ih1[j] + b_hh1[j];
        else if (g == 1) bias = b_ih2[j] + b_hh2[j];
        LDW(0); LDW(1); LDW(2); LDW(3); LDW(4); LDW(5);
        LDW(6); LDW(7); LDW(8); LDW(9); LDW(10); LDW(11);
        w12.x = wrow[48]; w12.y = wrow[49]; w12.z = wrow[50]; w12.w = 0.0f;
    }
    float* gdst = gall + g * GP + j;

    // update-lane extras
    float wi0 = 0.f, wi1 = 0.f, wi2 = 0.f, wi3 = 0.f;
    if (tid < H_) {
        wi0 = W_ih1[tid];
        wi1 = W_ih1[tid + H_];
        wi2 = W_ih1[tid + 2 * H_];
        wi3 = W_ih1[tid + 3 * H_];
    }
    const float blin = b_lin[0];

    float c1 = 0.f, c2 = 0.f;
    float* outp = out + (size_t)b * T_;

    // ---- prologue: h1(0) (h1(-1)=0 -> gates1 partial = bias1) ----
    if (g == 0 && act) gall[j] = bias;
    __syncthreads();
    if (tid < H_) {
        const float xv = xrow[0];
        float gi = fmaf(wi0, xv, gall[tid]);
        float gf = fmaf(wi1, xv, gall[tid + H_]);
        float gg = fmaf(wi2, xv, gall[tid + 2 * H_]);
        float go = fmaf(wi3, xv, gall[tid + 3 * H_]);
        float ig = sigf(gi), fg = sigf(gf), gv = tanh_fast(gg), og = sigf(go);
        c1 = fmaf(fg, c1, ig * gv);
        hs[0][tid] = og * tanh_fast(c1);
    }
    __syncthreads();

    // ========== hot loop: t = 0..998. 2 barriers/step. ==========
    for (int t = 0; t < L_ - 1; ++t) {
        // Phase A: three matvecs + (concurrently) output crew computes out(t-1)
        if (act) {
            MATVEC();
        } else if (tid >= 204 && tid < 208 && t > 0) {
            const int i  = tid - 204;
            const int k0 = i * 13;
            const int ke = (k0 + 13 < H_) ? k0 + 13 : H_;
            float p = 0.f;
            for (int k = k0; k < ke; ++k) p = fmaf(hs[1][k], wlin_s[k], p);
            p += __shfl_down(p, 2);
            p += __shfl_down(p, 1);
            if (i == 0) outp[t - 1] = p + blin;
        }
        __syncthreads();

        // Phase B: concurrent state updates
        if (tid >= 256 && tid < 256 + H_) {       // wave 4: h2(t)
            const int q2 = tid - 256;
            float gi = gall[GP + q2]          + gall[2*GP + q2];
            float gf = gall[GP + q2 +   H_]   + gall[2*GP + q2 +   H_];
            float gg = gall[GP + q2 + 2*H_]   + gall[2*GP + q2 + 2*H_];
            float go = gall[GP + q2 + 3*H_]   + gall[2*GP + q2 + 3*H_];
            float ig = sigf(gi), fg = sigf(gf), gv = tanh_fast(gg), og = sigf(go);
            c2 = fmaf(fg, c2, ig * gv);
            hs[1][q2] = og * tanh_fast(c2);
        }
        if (tid < H_) {                            // wave 0: h1(t+1)
            const float xv = xrow[t + 1];
            float gi = fmaf(wi0, xv, gall[tid]);
            float gf = fmaf(wi1, xv, gall[tid + H_]);
            float gg = fmaf(wi2, xv, gall[tid + 2 * H_]);
            float go = fmaf(wi3, xv, gall[tid + 3 * H_]);
            float ig = sigf(gi), fg = sigf(gf), gv = tanh_fast(gg), og = sigf(go);
            c1 = fmaf(fg, c1, ig * gv);
            hs[0][tid] = og * tanh_fast(c1);
        }
        __syncthreads();
    }

    // ========== future loop: t = 999..1099 (x <- out_s). 3 barriers. ==========
    for (int t = L_ - 1; t < T_; ++t) {
        if (act) {
            MATVEC();
        } else if (tid >= 204 && tid < 208 && t == L_ - 1) {
            // produce out(998) (hot loop emitted only up to out(997))
            const int i  = tid - 204;
            const int k0 = i * 13;
            const int ke = (k0 + 13 < H_) ? k0 + 13 : H_;
            float p = 0.f;
            for (int k = k0; k < ke; ++k) p = fmaf(hs[1][k], wlin_s[k], p);
            p += __shfl_down(p, 2);
            p += __shfl_down(p, 1);
            if (i == 0) outp[t - 1] = p + blin;
        }
        __syncthreads();

        if (tid >= 256 && tid < 320) {            // wave 4: h2(t) + out(t)
            float p = 0.f;
            const int q2 = tid - 256;
            if (q2 < H_) {
                float gi = gall[GP + q2]          + gall[2*GP + q2];
                float gf = gall[GP + q2 +   H_]   + gall[2*GP + q2 +   H_];
                float gg = gall[GP + q2 + 2*H_]   + gall[2*GP + q2 + 2*H_];
                float go = gall[GP + q2 + 3*H_]   + gall[2*GP + q2 + 3*H_];
                float ig = sigf(gi), fg = sigf(gf), gv = tanh_fast(gg), og = sigf(go);
                c2 = fmaf(fg, c2, ig * gv);
                float h2n = og * tanh_fast(c2);
                hs[1][q2] = h2n;
                p = h2n * wlin_s[q2];
            }
#pragma unroll
            for (int off = 32; off > 0; off >>= 1) p += __shfl_down(p, off);
            if (q2 == 0) { float o = p + blin; out_s = o; outp[t] = o; }
        }
        __syncthreads();                           // out_s visible to wave 0

        if (tid < H_) {                            // wave 0: h1(t+1)
            const float xv = out_s;
            float gi = fmaf(wi0, xv, gall[tid]);
            float gf = fmaf(wi1, xv, gall[tid + H_]);
            float gg = fmaf(wi2, xv, gall[tid + 2 * H_]);
            float go = fmaf(wi3, xv, gall[tid + 3 * H_]);
            float ig = sigf(gi), fg = sigf(gf), gv = tanh_fast(gg), og = sigf(go);
            c1 = fmaf(fg, c1, ig * gv);
            hs[0][tid] = og * tanh_fast(c1);
        }
        __syncthreads();
    }
}

extern "C" void kernel_launch(void* const* d_in, const int* in_sizes, int n_in,
                              void* d_out, int out_size, void* d_ws, size_t ws_size,
                              hipStream_t stream)
{
    const float* x     = (const float*)d_in[0];
    const float* W_ih1 = (const float*)d_in[1];
    const float* W_hh1 = (const float*)d_in[2];
    const float* b_ih1 = (const float*)d_in[3];
    const float* b_hh1 = (const float*)d_in[4];
    const float* W_ih2 = (const float*)d_in[5];
    const float* W_hh2 = (const float*)d_in[6];
    const float* b_ih2 = (const float*)d_in[7];
    const float* b_hh2 = (const float*)d_in[8];
    const float* W_lin = (const float*)d_in[9];
    const float* b_lin = (const float*)d_in[10];
    float* out = (float*)d_out;

    lstm_pred_kernel<<<B_, 768, 0, stream>>>(x, W_ih1, W_hh1, b_ih1, b_hh1,
                                             W_ih2, W_hh2, b_ih2, b_hh2,
                                             W_lin, b_lin, out);
}

// Round 5
// 1206.966 us; speedup vs baseline: 1.0758x; 1.0758x over previous
//
#include <hip/hip_runtime.h>

// LSTMPredictor: 2-layer LSTMCell (H=51), L=1000 steps + 100 autoregressive,
// B=256 chains. One block/batch element (grid=256=#CUs), 768 threads, 3 groups:
//   G0 (tid   0..203): row j of W_hh1 -> gates1 partial (for h1(t+1))
//   G1 (tid 256..459): row j of W_ih2 -> gatesA(t)
//   G2 (tid 512..715): row j of W_hh2 -> gatesB(t)
// R5 KEY FIX: the compiler has been rematerializing the loop-invariant weight
// loads INSIDE the step loop (VGPR_Count 52-56 across R1-R4 = weights never
// register-resident). We pin all 51 weight scalars with a volatile inline-asm
// "+v" barrier after loading -> values become opaque -> must stay in VGPRs.
// Structure otherwise identical to R3 (best so far): 2 barriers/step hot loop,
// 3 barriers/step for the 101 autoregressive steps.

#define B_   256
#define L_   1000
#define H_   51
#define HP   52
#define G4   204
#define GP   208
#define T_   1100

__device__ __forceinline__ float frcp(float v) { return __builtin_amdgcn_rcpf(v); }
__device__ __forceinline__ float sigf(float v) {
    return frcp(1.0f + __expf(-v));
}
__device__ __forceinline__ float tanh_fast(float v) {
    float a = fminf(fmaxf(v, -9.0f), 9.0f);
    float e = __expf(2.0f * a);
    return (e - 1.0f) * frcp(e + 1.0f);
}

// dot of one float4 h-chunk with 4 named weight scalars
#define DOT4(hv, p0, p1, p2, p3) do { \
    a0 = fmaf(p0, (hv).x, a0); a1 = fmaf(p1, (hv).y, a1); \
    a2 = fmaf(p2, (hv).z, a2); a3 = fmaf(p3, (hv).w, a3); } while (0)

#define MATVEC() do { \
    const float4* h4 = (const float4*)hs[s]; \
    float4 hv0 = h4[0], hv1 = h4[1], hv2 = h4[2], hv3 = h4[3]; \
    float4 hv4 = h4[4], hv5 = h4[5], hv6 = h4[6], hv7 = h4[7]; \
    float4 hv8 = h4[8], hv9 = h4[9], hv10 = h4[10], hv11 = h4[11], hv12 = h4[12]; \
    float a0 = bias, a1 = 0.f, a2 = 0.f, a3 = 0.f; \
    DOT4(hv0,  wr0,  wr1,  wr2,  wr3);  DOT4(hv1,  wr4,  wr5,  wr6,  wr7); \
    DOT4(hv2,  wr8,  wr9,  wr10, wr11); DOT4(hv3,  wr12, wr13, wr14, wr15); \
    DOT4(hv4,  wr16, wr17, wr18, wr19); DOT4(hv5,  wr20, wr21, wr22, wr23); \
    DOT4(hv6,  wr24, wr25, wr26, wr27); DOT4(hv7,  wr28, wr29, wr30, wr31); \
    DOT4(hv8,  wr32, wr33, wr34, wr35); DOT4(hv9,  wr36, wr37, wr38, wr39); \
    DOT4(hv10, wr40, wr41, wr42, wr43); DOT4(hv11, wr44, wr45, wr46, wr47); \
    a0 = fmaf(wr48, hv12.x, a0); a1 = fmaf(wr49, hv12.y, a1); a2 = fmaf(wr50, hv12.z, a2); \
    gdst[0] = (a0 + a1) + (a2 + a3); } while (0)

__global__ __launch_bounds__(768, 3)
void lstm_pred_kernel(const float* __restrict__ x,
                      const float* __restrict__ W_ih1, const float* __restrict__ W_hh1,
                      const float* __restrict__ b_ih1, const float* __restrict__ b_hh1,
                      const float* __restrict__ W_ih2, const float* __restrict__ W_hh2,
                      const float* __restrict__ b_ih2, const float* __restrict__ b_hh2,
                      const float* __restrict__ W_lin, const float* __restrict__ b_lin,
                      float* __restrict__ out)
{
    __shared__ float xrow[L_];
    __shared__ alignas(16) float gall[3 * GP];  // g1partial | gatesA | gatesB
    __shared__ alignas(16) float hs[2][HP];     // hs[0]=h1, hs[1]=h2
    __shared__ float out_s;

    const int tid = threadIdx.x;
    const int b   = blockIdx.x;
    const int g   = tid >> 8;
    const int j   = tid & 255;
    const bool act = (j < G4);
    const int  s   = (g == 2) ? 1 : 0;

    for (int i = tid; i < L_; i += 768) xrow[i] = x[(size_t)b * L_ + i];
    if (tid < HP) { hs[0][tid] = 0.0f; hs[1][tid] = 0.0f; }

    // ---- one weight row per thread: 51 NAMED scalars ----
    const float* wrow = (g == 0) ? (W_hh1 + j * H_)
                      : (g == 1) ? (W_ih2 + j * H_)
                                 : (W_hh2 + j * H_);
    float bias = 0.0f;
    float wr0=0.f,wr1=0.f,wr2=0.f,wr3=0.f,wr4=0.f,wr5=0.f,wr6=0.f,wr7=0.f,
          wr8=0.f,wr9=0.f,wr10=0.f,wr11=0.f,wr12=0.f,wr13=0.f,wr14=0.f,wr15=0.f,
          wr16=0.f,wr17=0.f,wr18=0.f,wr19=0.f,wr20=0.f,wr21=0.f,wr22=0.f,wr23=0.f,
          wr24=0.f,wr25=0.f,wr26=0.f,wr27=0.f,wr28=0.f,wr29=0.f,wr30=0.f,wr31=0.f,
          wr32=0.f,wr33=0.f,wr34=0.f,wr35=0.f,wr36=0.f,wr37=0.f,wr38=0.f,wr39=0.f,
          wr40=0.f,wr41=0.f,wr42=0.f,wr43=0.f,wr44=0.f,wr45=0.f,wr46=0.f,wr47=0.f,
          wr48=0.f,wr49=0.f,wr50=0.f;
    if (act) {
        if (g == 0)      bias = b_ih1[j] + b_hh1[j];
        else if (g == 1) bias = b_ih2[j] + b_hh2[j];
        wr0 =wrow[0];  wr1 =wrow[1];  wr2 =wrow[2];  wr3 =wrow[3];
        wr4 =wrow[4];  wr5 =wrow[5];  wr6 =wrow[6];  wr7 =wrow[7];
        wr8 =wrow[8];  wr9 =wrow[9];  wr10=wrow[10]; wr11=wrow[11];
        wr12=wrow[12]; wr13=wrow[13]; wr14=wrow[14]; wr15=wrow[15];
        wr16=wrow[16]; wr17=wrow[17]; wr18=wrow[18]; wr19=wrow[19];
        wr20=wrow[20]; wr21=wrow[21]; wr22=wrow[22]; wr23=wrow[23];
        wr24=wrow[24]; wr25=wrow[25]; wr26=wrow[26]; wr27=wrow[27];
        wr28=wrow[28]; wr29=wrow[29]; wr30=wrow[30]; wr31=wrow[31];
        wr32=wrow[32]; wr33=wrow[33]; wr34=wrow[34]; wr35=wrow[35];
        wr36=wrow[36]; wr37=wrow[37]; wr38=wrow[38]; wr39=wrow[39];
        wr40=wrow[40]; wr41=wrow[41]; wr42=wrow[42]; wr43=wrow[43];
        wr44=wrow[44]; wr45=wrow[45]; wr46=wrow[46]; wr47=wrow[47];
        wr48=wrow[48]; wr49=wrow[49]; wr50=wrow[50];
    }
    // PIN: values become opaque -> compiler cannot re-load them in the loop.
    asm volatile("" :
        "+v"(wr0),"+v"(wr1),"+v"(wr2),"+v"(wr3),"+v"(wr4),"+v"(wr5),"+v"(wr6),
        "+v"(wr7),"+v"(wr8),"+v"(wr9),"+v"(wr10),"+v"(wr11),"+v"(wr12),"+v"(wr13),
        "+v"(wr14),"+v"(wr15),"+v"(wr16),"+v"(wr17),"+v"(wr18),"+v"(wr19),
        "+v"(wr20),"+v"(wr21),"+v"(wr22),"+v"(wr23),"+v"(wr24),"+v"(wr25));
    asm volatile("" :
        "+v"(wr26),"+v"(wr27),"+v"(wr28),"+v"(wr29),"+v"(wr30),"+v"(wr31),
        "+v"(wr32),"+v"(wr33),"+v"(wr34),"+v"(wr35),"+v"(wr36),"+v"(wr37),
        "+v"(wr38),"+v"(wr39),"+v"(wr40),"+v"(wr41),"+v"(wr42),"+v"(wr43),
        "+v"(wr44),"+v"(wr45),"+v"(wr46),"+v"(wr47),"+v"(wr48),"+v"(wr49),
        "+v"(wr50),"+v"(bias));
    float* gdst = gall + g * GP + j;

    // update-lane extras
    float wi0 = 0.f, wi1 = 0.f, wi2 = 0.f, wi3 = 0.f, wlin = 0.f;
    if (tid < H_) {
        wi0 = W_ih1[tid];
        wi1 = W_ih1[tid + H_];
        wi2 = W_ih1[tid + 2 * H_];
        wi3 = W_ih1[tid + 3 * H_];
    }
    if (tid >= 256 && tid < 256 + H_) wlin = W_lin[tid - 256];
    const float blin = b_lin[0];

    float c1 = 0.f, c2 = 0.f;
    float* outp = out + (size_t)b * T_;

    // ---- prologue: h1(0) (h1(-1)=0 -> gates1 partial = bias1) ----
    if (g == 0 && act) gall[j] = bias;
    __syncthreads();
    if (tid < H_) {
        const float xv = xrow[0];
        float gi = fmaf(wi0, xv, gall[tid]);
        float gf = fmaf(wi1, xv, gall[tid + H_]);
        float gg = fmaf(wi2, xv, gall[tid + 2 * H_]);
        float go = fmaf(wi3, xv, gall[tid + 3 * H_]);
        float ig = sigf(gi), fg = sigf(gf), gv = tanh_fast(gg), og = sigf(go);
        c1 = fmaf(fg, c1, ig * gv);
        hs[0][tid] = og * tanh_fast(c1);
    }
    __syncthreads();

    // ========== hot loop: t = 0..998, 2 barriers/step ==========
    for (int t = 0; t < L_ - 1; ++t) {
        if (act) MATVEC();
        __syncthreads();

        // Phase B1 (wave 4): h2(t) update + output
        if (tid >= 256 && tid < 320) {
            float p = 0.f;
            const int q2 = tid - 256;
            if (q2 < H_) {
                float gi = gall[GP + q2]        + gall[2*GP + q2];
                float gf = gall[GP + q2 +   H_] + gall[2*GP + q2 +   H_];
                float gg = gall[GP + q2 + 2*H_] + gall[2*GP + q2 + 2*H_];
                float go = gall[GP + q2 + 3*H_] + gall[2*GP + q2 + 3*H_];
                float ig = sigf(gi), fg = sigf(gf), gv = tanh_fast(gg), og = sigf(go);
                c2 = fmaf(fg, c2, ig * gv);
                float h2n = og * tanh_fast(c2);
                hs[1][q2] = h2n;
                p = h2n * wlin;
            }
#pragma unroll
            for (int off = 32; off > 0; off >>= 1) p += __shfl_down(p, off);
            if (q2 == 0) outp[t] = p + blin;
        }
        // Phase B2 (wave 0, concurrent): h1(t+1)
        if (tid < H_) {
            const float xv = xrow[t + 1];
            float gi = fmaf(wi0, xv, gall[tid]);
            float gf = fmaf(wi1, xv, gall[tid + H_]);
            float gg = fmaf(wi2, xv, gall[tid + 2 * H_]);
            float go = fmaf(wi3, xv, gall[tid + 3 * H_]);
            float ig = sigf(gi), fg = sigf(gf), gv = tanh_fast(gg), og = sigf(go);
            c1 = fmaf(fg, c1, ig * gv);
            hs[0][tid] = og * tanh_fast(c1);
        }
        __syncthreads();
    }

    // ========== future loop: t = 999..1099 (x <- out_s), 3 barriers ==========
    for (int t = L_ - 1; t < T_; ++t) {
        if (act) MATVEC();
        __syncthreads();

        if (tid >= 256 && tid < 320) {
            float p = 0.f;
            const int q2 = tid - 256;
            if (q2 < H_) {
                float gi = gall[GP + q2]        + gall[2*GP + q2];
                float gf = gall[GP + q2 +   H_] + gall[2*GP + q2 +   H_];
                float gg = gall[GP + q2 + 2*H_] + gall[2*GP + q2 + 2*H_];
                float go = gall[GP + q2 + 3*H_] + gall[2*GP + q2 + 3*H_];
                float ig = sigf(gi), fg = sigf(gf), gv = tanh_fast(gg), og = sigf(go);
                c2 = fmaf(fg, c2, ig * gv);
                float h2n = og * tanh_fast(c2);
                hs[1][q2] = h2n;
                p = h2n * wlin;
            }
#pragma unroll
            for (int off = 32; off > 0; off >>= 1) p += __shfl_down(p, off);
            if (q2 == 0) { float o = p + blin; out_s = o; outp[t] = o; }
        }
        __syncthreads();   // out_s visible to wave 0

        if (tid < H_) {
            const float xv = out_s;
            float gi = fmaf(wi0, xv, gall[tid]);
            float gf = fmaf(wi1, xv, gall[tid + H_]);
            float gg = fmaf(wi2, xv, gall[tid + 2 * H_]);
            float go = fmaf(wi3, xv, gall[tid + 3 * H_]);
            float ig = sigf(gi), fg = sigf(gf), gv = tanh_fast(gg), og = sigf(go);
            c1 = fmaf(fg, c1, ig * gv);
            hs[0][tid] = og * tanh_fast(c1);
        }
        __syncthreads();
    }
}

extern "C" void kernel_launch(void* const* d_in, const int* in_sizes, int n_in,
                              void* d_out, int out_size, void* d_ws, size_t ws_size,
                              hipStream_t stream)
{
    const float* x     = (const float*)d_in[0];
    const float* W_ih1 = (const float*)d_in[1];
    const float* W_hh1 = (const float*)d_in[2];
    const float* b_ih1 = (const float*)d_in[3];
    const float* b_hh1 = (const float*)d_in[4];
    const float* W_ih2 = (const float*)d_in[5];
    const float* W_hh2 = (const float*)d_in[6];
    const float* b_ih2 = (const float*)d_in[7];
    const float* b_hh2 = (const float*)d_in[8];
    const float* W_lin = (const float*)d_in[9];
    const float* b_lin = (const float*)d_in[10];
    float* out = (float*)d_out;

    lstm_pred_kernel<<<B_, 768, 0, stream>>>(x, W_ih1, W_hh1, b_ih1, b_hh1,
                                             W_ih2, W_hh2, b_ih2, b_hh2,
                                             W_lin, b_lin, out);
}